// Round 5
// baseline (473.734 us; speedup 1.0000x reference)
//
#include <hip/hip_runtime.h>
#include <hip/hip_bf16.h>
#include <cstdint>

typedef __attribute__((ext_vector_type(8))) short bf16x8;
typedef __attribute__((ext_vector_type(4))) float f32x4;
typedef __attribute__((ext_vector_type(8))) unsigned short u16x8;

__device__ __forceinline__ unsigned short f2bf(float f) {
    unsigned int u = __float_as_uint(f);
    unsigned int r = (u + 0x7fffu + ((u >> 16) & 1u)) >> 16;
    return (unsigned short)r;
}

__device__ __forceinline__ float tanh_fast(float x) {
    return 1.0f - 2.0f / (__expf(2.0f * x) + 1.0f);
}

#define GLDS(SRC, DST) __builtin_amdgcn_global_load_lds(                         \
        (const __attribute__((address_space(1))) void*)(SRC),                    \
        (__attribute__((address_space(3))) void*)(DST), 16, 0, 0)

// ---------- K-1: fp32 -> bf16 key into fragment-tiled layout ----------
// per (panel p of 256 rows, ktile kt of 32 k): 8192 ushorts =
// [rowblk 0..15][lane 0..63][8] ; row = p*256+rowblk*16+(lane&15), k = kt*32+(lane>>4)*8+j
__global__ __launch_bounds__(256) void key_tile_kernel(
        const float* __restrict__ in, unsigned short* __restrict__ out) {
    const int p = blockIdx.x;   // 0..255
    const int kt = blockIdx.y;  // 0..31
    const int t = threadIdx.x;
#pragma unroll
    for (int it = 0; it < 4; ++it) {
        const int c = it * 256 + t;           // 0..1023
        const int lane = c & 63, rowblk = c >> 6;
        const int row = p * 256 + rowblk * 16 + (lane & 15);
        const int k = kt * 32 + (lane >> 4) * 8;
        const float* src = in + (size_t)row * 1024 + k;
        const float4 v0 = *reinterpret_cast<const float4*>(src);
        const float4 v1 = *reinterpret_cast<const float4*>(src + 4);
        u16x8 u;
        u[0] = f2bf(v0.x); u[1] = f2bf(v0.y); u[2] = f2bf(v0.z); u[3] = f2bf(v0.w);
        u[4] = f2bf(v1.x); u[5] = f2bf(v1.y); u[6] = f2bf(v1.z); u[7] = f2bf(v1.w);
        *reinterpret_cast<u16x8*>(out + (size_t)(p * 32 + kt) * 8192 + c * 8) = u;
    }
}

// ---------- K0: w_v -> bf16 fragment-tiled B per head-pair ----------
// per (hp, kt): 8192 ushorts = [colblk 0..15][lane][8]; col e = hp*256+colblk*16+(lane&15)
__global__ __launch_bounds__(256) void wv_tile_kernel(
        const float* __restrict__ wv, unsigned short* __restrict__ out) {
    __shared__ float tile[32][260];
    const int hp = blockIdx.x;  // 0..3
    const int kt = blockIdx.y;  // 0..31
    const int t = threadIdx.x;
    for (int i = t; i < 2048; i += 256) {   // 32 f-rows x 64 float4
        const int f = i >> 6, e4 = (i & 63) * 4;
        const float4 v = *reinterpret_cast<const float4*>(
            wv + (size_t)(kt * 32 + f) * 1024 + hp * 256 + e4);
        tile[f][e4 + 0] = v.x; tile[f][e4 + 1] = v.y;
        tile[f][e4 + 2] = v.z; tile[f][e4 + 3] = v.w;
    }
    __syncthreads();
#pragma unroll
    for (int it = 0; it < 4; ++it) {
        const int c = it * 256 + t;
        const int lane = c & 63, colblk = c >> 6;
        const int e_l = colblk * 16 + (lane & 15);
        const int f0 = (lane >> 4) * 8;
        u16x8 u;
#pragma unroll
        for (int jj = 0; jj < 8; ++jj) u[jj] = f2bf(tile[f0 + jj][e_l]);
        *reinterpret_cast<u16x8*>(out + (size_t)(hp * 32 + kt) * 8192 + c * 8) = u;
    }
}

// ---------- K1: q projection ----------
__global__ __launch_bounds__(128) void qproj_kernel(
        const float* __restrict__ query, const float* __restrict__ w_q,
        float* __restrict__ ws_q) {
    __shared__ float qs[1024];
    int bh = blockIdx.x;
    int b = bh >> 3, h = bh & 7;
    int t = threadIdx.x;
    for (int i = t; i < 1024; i += 128) qs[i] = query[(size_t)b * 1024 + i];
    __syncthreads();
    float acc = 0.f;
    const float* wcol = w_q + h * 128 + t;
    for (int f = 0; f < 1024; ++f) acc += qs[f] * wcol[(size_t)f * 1024];
    ws_q[(size_t)bh * 128 + t] = acc;
}

// ---------- K2: conv1d location features ----------
__global__ __launch_bounds__(256) void loc_conv_kernel(
        const float* __restrict__ pa, const float* __restrict__ conv_w,
        const float* __restrict__ conv_b, float* __restrict__ ws_loc) {
    __shared__ float pas[8][258];
    __shared__ float cw[240];
    __shared__ float cb[16];
    int b = blockIdx.x, k0 = blockIdx.y * 256;
    int t = threadIdx.x;
    for (int i = t; i < 8 * 258; i += 256) {
        int hh = i / 258, kk = i % 258;
        int gk = k0 + kk - 1;
        pas[hh][kk] = (gk >= 0 && gk < 4096) ? pa[((size_t)(b * 8 + hh)) * 4096 + gk] : 0.f;
    }
    if (t < 240) cw[t] = conv_w[t];
    if (t < 10) cb[t] = conv_b[t];
    __syncthreads();
#pragma unroll
    for (int c = 0; c < 10; ++c) {
        float acc = cb[c];
#pragma unroll
        for (int hh = 0; hh < 8; ++hh) {
            acc += pas[hh][t] * cw[(c * 8 + hh) * 3 + 0]
                 + pas[hh][t + 1] * cw[(c * 8 + hh) * 3 + 1]
                 + pas[hh][t + 2] * cw[(c * 8 + hh) * 3 + 2];
        }
        ws_loc[((size_t)(b * 10 + c)) * 4096 + k0 + t] = acc;
    }
}

// ---------- K2b: le[b,k,d] = tanh(sum_c loc[b,c,k]*w_u[c,d]) ----------
__global__ __launch_bounds__(256) void loc_energy_kernel(
        const float* __restrict__ ws_loc, const float* __restrict__ w_u,
        float* __restrict__ le) {
    __shared__ float loc_s[10][128];
    __shared__ float wu_s[10][128];
    const int b = blockIdx.x, k0 = blockIdx.y * 128;
    const int t = threadIdx.x;
    for (int i = t; i < 1280; i += 256) {
        const int c = i >> 7, r = i & 127;
        loc_s[c][r] = ws_loc[((size_t)(b * 10 + c)) * 4096 + k0 + r];
        wu_s[c][r] = w_u[i];
    }
    __syncthreads();
    const int k = t >> 1;
    const int d0 = (t & 1) * 64;
    float lc[10];
#pragma unroll
    for (int c = 0; c < 10; ++c) lc[c] = loc_s[c][k];
    float* dst = le + ((size_t)(b * 4096) + k0 + k) * 128 + d0;
#pragma unroll
    for (int dd = 0; dd < 64; dd += 4) {
        float4 o;
#pragma unroll
        for (int jj = 0; jj < 4; ++jj) {
            float s = 0.f;
#pragma unroll
            for (int c = 0; c < 10; ++c) s += lc[c] * wu_s[c][d0 + dd + jj];
            ((float*)&o)[jj] = tanh_fast(s);
        }
        *reinterpret_cast<float4*>(dst + dd) = o;
    }
}

// ---------- K3: deep-pipelined bf16 MFMA GEMM + energy + score ----------
// BM=256 rows, BN=256 (2 heads), BK=32; 512 thr, 8 waves (2M x 4N), wave C = 128x64.
// Ring of 3 K-tile LDS buffers; stage tile kt+2 while computing kt; vmcnt(4)/K-tile.
#define NT 32
__global__ __launch_bounds__(512) void gemm_score_kernel(
        const unsigned short* __restrict__ keyT, const unsigned short* __restrict__ wvT,
        const float* __restrict__ le, const float* __restrict__ ws_q,
        const float* __restrict__ bias, const float* __restrict__ score_w,
        const float* __restrict__ score_b, float* __restrict__ align_out) {
    // slot: A = [0..8191] ushorts (16 rowblks x 64 lanes x 8), B = [8192..16383]
    __shared__ __align__(16) unsigned short ring[3][16384];   // 96 KB
    __shared__ float qb_sm[256], sw_sm[256];
    __shared__ float partial[256][4];                          // [row][head*2+half]

    const int t = threadIdx.x;
    const int lane = t & 63, wid = t >> 6;
    const int wm = wid >> 2, wn = wid & 3;       // 2 x 4

    const int fid = blockIdx.x;                  // 1024 blocks
    const int x = fid & 7, j = fid >> 3;         // XCD swizzle: same-panel blocks on one XCD
    const int bm = x * 32 + (j >> 2);            // panel 0..255
    const int hp = j & 3;                        // head-pair
    const int b = bm >> 4;
    const int kk0 = (bm & 15) << 8;              // key-row offset within batch

    if (t < 256) {
        const int hh = t >> 7, d = t & 127;
        qb_sm[t] = ws_q[(size_t)(b * 8 + hp * 2 + hh) * 128 + d] + bias[d];
        sw_sm[t] = score_w[d];
    }

    const unsigned short* aBase = keyT + (size_t)bm * (NT * 8192);
    const unsigned short* bBase = wvT + (size_t)hp * (NT * 8192);

#define SA(SLOT, KT, RND) GLDS(aBase + (size_t)(KT) * 8192 + (RND) * 4096 + t * 8, \
                               &ring[SLOT][(RND) * 4096 + t * 8])
#define SB(SLOT, KT, RND) GLDS(bBase + (size_t)(KT) * 8192 + (RND) * 4096 + t * 8, \
                               &ring[SLOT][8192 + (RND) * 4096 + t * 8])

    f32x4 acc[8][4] = {};

    // prologue: stage T0 -> slot0, T1 -> slot1 (8 loads); wait oldest 4 (= all of T0)
    SA(0, 0, 0); SA(0, 0, 1); SB(0, 0, 0); SB(0, 0, 1);
    SA(1, 1, 0); SA(1, 1, 1); SB(1, 1, 0); SB(1, 1, 1);
    asm volatile("s_waitcnt vmcnt(4)" ::: "memory");
    __builtin_amdgcn_s_barrier();
    asm volatile("" ::: "memory");

    int s = 0, sn = 1, sp = 2;
    for (int kt = 0; kt < NT; ++kt) {
        const bool pf = (kt + 2 < NT);
        bf16x8 bg[4];
        // ---- phase 0: stage A(kt+2); compute mf 0..3 ----
        if (pf) { SA(sp, kt + 2, 0); SA(sp, kt + 2, 1); }
        bf16x8 af0[4];
#pragma unroll
        for (int mf = 0; mf < 4; ++mf)
            af0[mf] = *reinterpret_cast<const bf16x8*>(&ring[s][(wm * 8 + mf) * 512 + lane * 8]);
#pragma unroll
        for (int nf = 0; nf < 4; ++nf)
            bg[nf] = *reinterpret_cast<const bf16x8*>(&ring[s][8192 + (wn * 4 + nf) * 512 + lane * 8]);
        __builtin_amdgcn_s_barrier();
        asm volatile("" ::: "memory");
        __builtin_amdgcn_s_setprio(1);
#pragma unroll
        for (int mf = 0; mf < 4; ++mf)
#pragma unroll
            for (int nf = 0; nf < 4; ++nf)
                acc[mf][nf] = __builtin_amdgcn_mfma_f32_16x16x32_bf16(
                    af0[mf], bg[nf], acc[mf][nf], 0, 0, 0);
        __builtin_amdgcn_s_setprio(0);
        __builtin_amdgcn_s_barrier();
        asm volatile("" ::: "memory");
        // ---- phase 1: stage B(kt+2); compute mf 4..7 ----
        if (pf) { SB(sp, kt + 2, 0); SB(sp, kt + 2, 1); }
        bf16x8 af1[4];
#pragma unroll
        for (int mf = 0; mf < 4; ++mf)
            af1[mf] = *reinterpret_cast<const bf16x8*>(&ring[s][(wm * 8 + 4 + mf) * 512 + lane * 8]);
        __builtin_amdgcn_s_barrier();
        asm volatile("" ::: "memory");
        __builtin_amdgcn_s_setprio(1);
#pragma unroll
        for (int mf = 0; mf < 4; ++mf)
#pragma unroll
            for (int nf = 0; nf < 4; ++nf)
                acc[4 + mf][nf] = __builtin_amdgcn_mfma_f32_16x16x32_bf16(
                    af1[mf], bg[nf], acc[4 + mf][nf], 0, 0, 0);
        __builtin_amdgcn_s_setprio(0);
        // ---- K-tile boundary: tile kt+1 must be landed; keep kt+2's 4 in flight ----
        if (kt < NT - 2) {
            asm volatile("s_waitcnt vmcnt(4)" ::: "memory");
        } else if (kt == NT - 2) {
            asm volatile("s_waitcnt vmcnt(0)" ::: "memory");
        }
        __builtin_amdgcn_s_barrier();
        asm volatile("" ::: "memory");
        const int tmp = s; s = sn; sn = sp; sp = tmp;
    }

    // ---- epilogue: score = sum_d tanh(kproj + q + bias + le) * sw ----
    __syncthreads();
    const float K2 = 2.8853900817779268f;
    const float sb = score_b[0];
    const int g = lane >> 4;
    float kqb[4], swv[4];
#pragma unroll
    for (int nf = 0; nf < 4; ++nf) {
        const int d_le = (wn & 1) * 64 + nf * 16 + (lane & 15);
        const int qi = (wn >> 1) * 128 + d_le;
        kqb[nf] = qb_sm[qi] * K2;
        swv[nf] = sw_sm[qi];
    }
    const float* leB = le + ((size_t)(b * 4096 + kk0) + wm * 128 + g * 4) * 128
                       + (wn & 1) * 64 + (lane & 15);
#pragma unroll
    for (int amf = 0; amf < 8; ++amf) {
        float lv[16];
#pragma unroll
        for (int jj = 0; jj < 4; ++jj)
#pragma unroll
            for (int nf = 0; nf < 4; ++nf)
                lv[jj * 4 + nf] = leB[(size_t)(amf * 16 + jj) * 128 + nf * 16];
#pragma unroll
        for (int jj = 0; jj < 4; ++jj) {
            const int row_l = wm * 128 + amf * 16 + g * 4 + jj;
            float sum = 0.f;
#pragma unroll
            for (int nf = 0; nf < 4; ++nf) {
                const float m = fmaf(K2, lv[jj * 4 + nf], kqb[nf]);
                const float tt = fmaf(K2, acc[amf][nf][jj], m);
                const float y = __builtin_amdgcn_exp2f(tt);
                const float r = fmaf(-2.0f, __builtin_amdgcn_rcpf(y + 1.0f), 1.0f);
                sum = fmaf(r, swv[nf], sum);
            }
            sum += __shfl_xor(sum, 1);
            sum += __shfl_xor(sum, 2);
            sum += __shfl_xor(sum, 4);
            sum += __shfl_xor(sum, 8);
            if ((lane & 15) == 0) partial[row_l][(wn >> 1) * 2 + (wn & 1)] = sum;
        }
    }
    __syncthreads();
    {
        const int r = t >> 1, hh = t & 1;
        const float sc = partial[r][hh * 2] + partial[r][hh * 2 + 1] + sb;
        align_out[(size_t)(b * 8 + hp * 2 + hh) * 4096 + kk0 + r] = sc;
    }
}

// ---------- K4: softmax over k ----------
__global__ __launch_bounds__(256) void softmax_kernel(float* __restrict__ align_o) {
    const int bh = blockIdx.x;
    float* row = align_o + (size_t)bh * 4096;
    const int t = threadIdx.x;
    float v[16];
    float m = -1e30f;
#pragma unroll
    for (int i = 0; i < 16; ++i) {
        v[i] = row[i * 256 + t];
        m = fmaxf(m, v[i]);
    }
#pragma unroll
    for (int off = 32; off; off >>= 1) m = fmaxf(m, __shfl_xor(m, off));
    __shared__ float sm[4], ss[4];
    const int wid = t >> 6;
    if ((t & 63) == 0) sm[wid] = m;
    __syncthreads();
    m = fmaxf(fmaxf(sm[0], sm[1]), fmaxf(sm[2], sm[3]));
    float s = 0.f;
#pragma unroll
    for (int i = 0; i < 16; ++i) {
        v[i] = __expf(v[i] - m);
        s += v[i];
    }
#pragma unroll
    for (int off = 32; off; off >>= 1) s += __shfl_xor(s, off);
    if ((t & 63) == 0) ss[wid] = s;
    __syncthreads();
    s = ss[0] + ss[1] + ss[2] + ss[3];
    const float inv = 1.f / s;
#pragma unroll
    for (int i = 0; i < 16; ++i) row[i * 256 + t] = v[i] * inv;
}

// ---------- K5: split-K context partials ----------
__global__ __launch_bounds__(256) void ctx_partial_kernel(
        const float* __restrict__ value, const float* __restrict__ align_o,
        float* __restrict__ pctx) {
    const int s = blockIdx.x;    // 0..31
    const int bh = blockIdx.y;   // 0..127
    const int b = bh >> 3, h = bh & 7;
    const int t = threadIdx.x;
    const int d4 = (t & 31) * 4;
    const int kg = t >> 5;
    const float* arow = align_o + (size_t)bh * 4096 + s * 128;
    const float* vbase = value + ((size_t)(b * 4096 + s * 128)) * 1024 + h * 128 + d4;
    float4 acc = {0.f, 0.f, 0.f, 0.f};
    for (int i = 0; i < 16; ++i) {
        const int kk = i * 8 + kg;
        const float a = arow[kk];
        const float4 v = *reinterpret_cast<const float4*>(vbase + (size_t)kk * 1024);
        acc.x += a * v.x; acc.y += a * v.y; acc.z += a * v.z; acc.w += a * v.w;
    }
    __shared__ float sm2[8][128];
    *reinterpret_cast<float4*>(&sm2[kg][d4]) = acc;
    __syncthreads();
    if (t < 128) {
        float s0 = 0.f;
#pragma unroll
        for (int gg = 0; gg < 8; ++gg) s0 += sm2[gg][t];
        pctx[((size_t)bh * 32 + s) * 128 + t] = s0;
    }
}

// ---------- K6: reduce context partials ----------
__global__ __launch_bounds__(128) void ctx_reduce_kernel(
        const float* __restrict__ pctx, float* __restrict__ out) {
    const int bh = blockIdx.x;
    const int t = threadIdx.x;
    float acc = 0.f;
    for (int s2 = 0; s2 < 32; ++s2) acc += pctx[((size_t)bh * 32 + s2) * 128 + t];
    out[(size_t)bh * 128 + t] = acc;
}

extern "C" void kernel_launch(void* const* d_in, const int* in_sizes, int n_in,
                              void* d_out, int out_size, void* d_ws, size_t ws_size,
                              hipStream_t stream) {
    const float* query   = (const float*)d_in[0];
    const float* key_in  = (const float*)d_in[1];
    const float* value   = (const float*)d_in[2];
    const float* pa      = (const float*)d_in[3];
    const float* conv_w  = (const float*)d_in[4];
    const float* conv_b  = (const float*)d_in[5];
    const float* w_u     = (const float*)d_in[6];
    const float* w_q     = (const float*)d_in[7];
    const float* w_v     = (const float*)d_in[8];
    const float* bias    = (const float*)d_in[9];
    const float* score_w = (const float*)d_in[10];
    const float* score_b = (const float*)d_in[11];

    float* out = (float*)d_out;
    float* ctx_out = out;                 // [128,128]
    float* align_out = out + 16384;       // [16,8,4096]

    char* ws = (char*)d_ws;
    const size_t OFF_Q    = 0;                        // 64 KB
    const size_t OFF_LOC  = 65536;                    // 2.62 MB
    const size_t OFF_WVT  = OFF_LOC + 2621440;        // 2 MB (tiled bf16)
    const size_t OFF_PCTX = OFF_WVT + 2097152;        // 2 MB
    const size_t OFF_LE   = OFF_PCTX + 2097152;       // 33.55 MB
    const size_t OFF_KBF  = OFF_LE + 33554432;        // 128 MB (tiled bf16)

    float* ws_q            = (float*)(ws + OFF_Q);
    float* ws_loc          = (float*)(ws + OFF_LOC);
    unsigned short* ws_wvT = (unsigned short*)(ws + OFF_WVT);
    float* ws_pctx         = (float*)(ws + OFF_PCTX);
    float* ws_le           = (float*)(ws + OFF_LE);
    unsigned short* ws_kbf = (unsigned short*)(ws + OFF_KBF);

    hipLaunchKernelGGL(wv_tile_kernel, dim3(4, 32), dim3(256), 0, stream, w_v, ws_wvT);
    hipLaunchKernelGGL(qproj_kernel, dim3(128), dim3(128), 0, stream, query, w_q, ws_q);
    hipLaunchKernelGGL(loc_conv_kernel, dim3(16, 16), dim3(256), 0, stream, pa, conv_w, conv_b, ws_loc);
    hipLaunchKernelGGL(loc_energy_kernel, dim3(16, 32), dim3(256), 0, stream, ws_loc, w_u, ws_le);
    hipLaunchKernelGGL(key_tile_kernel, dim3(256, 32), dim3(256), 0, stream, key_in, ws_kbf);
    hipLaunchKernelGGL(gemm_score_kernel, dim3(1024), dim3(512), 0, stream,
                       ws_kbf, ws_wvT, ws_le, ws_q, bias, score_w, score_b, align_out);
    hipLaunchKernelGGL(softmax_kernel, dim3(128), dim3(256), 0, stream, align_out);
    hipLaunchKernelGGL(ctx_partial_kernel, dim3(32, 128), dim3(256), 0, stream, value, align_out, ws_pctx);
    hipLaunchKernelGGL(ctx_reduce_kernel, dim3(128), dim3(128), 0, stream, ws_pctx, ctx_out);
}

// Round 6
// 405.653 us; speedup vs baseline: 1.1678x; 1.1678x over previous
//
#include <hip/hip_runtime.h>
#include <hip/hip_bf16.h>
#include <cstdint>

typedef __attribute__((ext_vector_type(8))) short bf16x8;
typedef __attribute__((ext_vector_type(4))) float f32x4;
typedef __attribute__((ext_vector_type(8))) unsigned short u16x8;

__device__ __forceinline__ unsigned short f2bf(float f) {
    unsigned int u = __float_as_uint(f);
    unsigned int r = (u + 0x7fffu + ((u >> 16) & 1u)) >> 16;
    return (unsigned short)r;
}

__device__ __forceinline__ float tanh_fast(float x) {
    return 1.0f - 2.0f / (__expf(2.0f * x) + 1.0f);
}

#define GLDS(SRC, DST) __builtin_amdgcn_global_load_lds(                         \
        (const __attribute__((address_space(1))) void*)(SRC),                    \
        (__attribute__((address_space(3))) void*)(DST), 16, 0, 0)

// ---------- K0: w_v -> bf16 fragment-tiled B (per head) ----------
// out[h][kt][chunk c=cb*64+kg*16+cc][8]; col e=h*128+cb*16+cc, k(f)=kt*32+kg*8..+8
__global__ __launch_bounds__(256) void wv_tile_kernel(
        const float* __restrict__ wv, unsigned short* __restrict__ out) {
    __shared__ float tile[32][129];
    const int h = blockIdx.x;    // 0..7
    const int kt = blockIdx.y;   // 0..31
    const int t = threadIdx.x;
    for (int i = t; i < 1024; i += 256) {
        const int fl = i >> 5;
        const int e4 = (i & 31) * 4;
        const float4 v = *reinterpret_cast<const float4*>(
            wv + (size_t)(kt * 32 + fl) * 1024 + h * 128 + e4);
        tile[fl][e4 + 0] = v.x; tile[fl][e4 + 1] = v.y;
        tile[fl][e4 + 2] = v.z; tile[fl][e4 + 3] = v.w;
    }
    __syncthreads();
#pragma unroll
    for (int cc2 = 0; cc2 < 2; ++cc2) {
        const int c = cc2 * 256 + t;
        const int cb = c >> 6, kg = (c >> 4) & 3, ccl = c & 15;
        const int e_local = cb * 16 + ccl;
        u16x8 u;
#pragma unroll
        for (int jj = 0; jj < 8; ++jj) u[jj] = f2bf(tile[kg * 8 + jj][e_local]);
        *reinterpret_cast<u16x8*>(out + (((size_t)h * 32 + kt) * 512 + c) * 8) = u;
    }
}

// ---------- K1: q projection ----------
__global__ __launch_bounds__(128) void qproj_kernel(
        const float* __restrict__ query, const float* __restrict__ w_q,
        float* __restrict__ ws_q) {
    __shared__ float qs[1024];
    int bh = blockIdx.x;
    int b = bh >> 3, h = bh & 7;
    int t = threadIdx.x;
    for (int i = t; i < 1024; i += 128) qs[i] = query[(size_t)b * 1024 + i];
    __syncthreads();
    float acc = 0.f;
    const float* wcol = w_q + h * 128 + t;
    for (int f = 0; f < 1024; ++f) acc += qs[f] * wcol[(size_t)f * 1024];
    ws_q[(size_t)bh * 128 + t] = acc;
}

// ---------- K2: conv1d location features ----------
__global__ __launch_bounds__(256) void loc_conv_kernel(
        const float* __restrict__ pa, const float* __restrict__ conv_w,
        const float* __restrict__ conv_b, float* __restrict__ ws_loc) {
    __shared__ float pas[8][258];
    __shared__ float cw[240];
    __shared__ float cb[16];
    int b = blockIdx.x, k0 = blockIdx.y * 256;
    int t = threadIdx.x;
    for (int i = t; i < 8 * 258; i += 256) {
        int hh = i / 258, kk = i % 258;
        int gk = k0 + kk - 1;
        pas[hh][kk] = (gk >= 0 && gk < 4096) ? pa[((size_t)(b * 8 + hh)) * 4096 + gk] : 0.f;
    }
    if (t < 240) cw[t] = conv_w[t];
    if (t < 10) cb[t] = conv_b[t];
    __syncthreads();
#pragma unroll
    for (int c = 0; c < 10; ++c) {
        float acc = cb[c];
#pragma unroll
        for (int hh = 0; hh < 8; ++hh) {
            acc += pas[hh][t] * cw[(c * 8 + hh) * 3 + 0]
                 + pas[hh][t + 1] * cw[(c * 8 + hh) * 3 + 1]
                 + pas[hh][t + 2] * cw[(c * 8 + hh) * 3 + 2];
        }
        ws_loc[((size_t)(b * 10 + c)) * 4096 + k0 + t] = acc;
    }
}

// ---------- K2b: le[b,k,d] = tanh(sum_c loc[b,c,k]*w_u[c,d]) ----------
__global__ __launch_bounds__(256) void loc_energy_kernel(
        const float* __restrict__ ws_loc, const float* __restrict__ w_u,
        float* __restrict__ le) {
    __shared__ float loc_s[10][128];
    __shared__ float wu_s[10][128];
    const int b = blockIdx.x, k0 = blockIdx.y * 128;
    const int t = threadIdx.x;
    for (int i = t; i < 1280; i += 256) {
        const int c = i >> 7, r = i & 127;
        loc_s[c][r] = ws_loc[((size_t)(b * 10 + c)) * 4096 + k0 + r];
        wu_s[c][r] = w_u[i];
    }
    __syncthreads();
    const int k = t >> 1;
    const int d0 = (t & 1) * 64;
    float lc[10];
#pragma unroll
    for (int c = 0; c < 10; ++c) lc[c] = loc_s[c][k];
    float* dst = le + ((size_t)(b * 4096) + k0 + k) * 128 + d0;
#pragma unroll
    for (int dd = 0; dd < 64; dd += 4) {
        float4 o;
#pragma unroll
        for (int jj = 0; jj < 4; ++jj) {
            float s = 0.f;
#pragma unroll
            for (int c = 0; c < 10; ++c) s += lc[c] * wu_s[c][d0 + dd + jj];
            ((float*)&o)[jj] = tanh_fast(s);
        }
        *reinterpret_cast<float4*>(dst + dd) = o;
    }
}

// ---------- K3: fused bf16 MFMA GEMM + energy + score ----------
// BM=128, BN=128 (one head), BK=32; 4 waves 2x2; dbuf, 1 barrier/K-step.
// A: fp32 loaded to regs one iter ahead, converted, ds_written fragment-tiled.
// B: pre-tiled bf16 via global_load_lds.
__global__ __launch_bounds__(256) void gemm_score_kernel(
        const float* __restrict__ key_in, const unsigned short* __restrict__ wvT_tiled,
        const float* __restrict__ le,
        const float* __restrict__ ws_q, const float* __restrict__ bias,
        const float* __restrict__ score_w, const float* __restrict__ score_b,
        float* __restrict__ align_out) {
    __shared__ __align__(16) unsigned short As[2][4096];
    __shared__ __align__(16) unsigned short Bs[2][4096];
    __shared__ float qb_sm[128], sw_sm[128];
    __shared__ float partial[256];

    const int t = threadIdx.x;
    const int lane = t & 63, wid = t >> 6;
    const int wm = wid >> 1, wn = wid & 1;

    // XCD swizzle: 8 head-blocks of one A-panel consecutive on one XCD
    const int fid = blockIdx.x;
    const int x = fid & 7, j = fid >> 3;
    const int bm = x * 64 + (j >> 3);    // panel 0..511 (128 rows)
    const int h = j & 7;
    const int b = bm >> 5;
    const int kk0 = (bm & 31) << 7;

    if (t < 128) {
        qb_sm[t] = ws_q[(size_t)(b * 8 + h) * 128 + t] + bias[t];
        sw_sm[t] = score_w[t];
    }

    const unsigned short* bT = wvT_tiled + (size_t)h * 131072;

    // A-staging geometry: thread t owns row r_=t>>1, k-halfseg (t&1)*16 of each K-tile
    const int r_ = t >> 1;
    const float* aRow = key_in + ((size_t)(b * 4096 + kk0) + r_) * 1024 + (t & 1) * 16;
    // dest chunk: c0 = rowblk*64 + kg*16 + (r_&15), kg = 2*(t&1); +16 for kg+1
    const int dst0 = ((r_ >> 4) * 64 + (t & 1) * 32 + (r_ & 15)) * 8;

    float4 st0, st1, st2, st3;

#define LOADA(KT) {                                                               \
        const float* p_ = aRow + (KT) * 32;                                       \
        st0 = *reinterpret_cast<const float4*>(p_);                               \
        st1 = *reinterpret_cast<const float4*>(p_ + 4);                           \
        st2 = *reinterpret_cast<const float4*>(p_ + 8);                           \
        st3 = *reinterpret_cast<const float4*>(p_ + 12); }

#define WRITEA(BUF) {                                                             \
        u16x8 u0_, u1_;                                                           \
        u0_[0] = f2bf(st0.x); u0_[1] = f2bf(st0.y);                               \
        u0_[2] = f2bf(st0.z); u0_[3] = f2bf(st0.w);                               \
        u0_[4] = f2bf(st1.x); u0_[5] = f2bf(st1.y);                               \
        u0_[6] = f2bf(st1.z); u0_[7] = f2bf(st1.w);                               \
        u1_[0] = f2bf(st2.x); u1_[1] = f2bf(st2.y);                               \
        u1_[2] = f2bf(st2.z); u1_[3] = f2bf(st2.w);                               \
        u1_[4] = f2bf(st3.x); u1_[5] = f2bf(st3.y);                               \
        u1_[6] = f2bf(st3.z); u1_[7] = f2bf(st3.w);                               \
        *reinterpret_cast<u16x8*>(&As[BUF][dst0]) = u0_;                          \
        *reinterpret_cast<u16x8*>(&As[BUF][dst0 + 128]) = u1_; }

#define STAGE_B(BUF, KT) {                                                        \
        GLDS(bT + (KT) * 4096 + t * 8, &Bs[BUF][t * 8]);                          \
        GLDS(bT + (KT) * 4096 + 2048 + t * 8, &Bs[BUF][2048 + t * 8]); }

    f32x4 acc[4][4] = {};

    // prologue: A(0) -> As[0]; B(0) -> Bs[0]; preload A(1) regs
    LOADA(0);
    STAGE_B(0, 0);
    WRITEA(0);
    LOADA(1);
    __syncthreads();

    for (int kt = 0; kt < 32; ++kt) {
        const int cur = kt & 1;
        if (kt < 31) {
            STAGE_B(cur ^ 1, kt + 1);
            WRITEA(cur ^ 1);            // uses regs loaded last iteration
        }
        if (kt < 30) LOADA(kt + 2);     // issue early; lands before next iter's WRITEA
        bf16x8 af[4], bg[4];
#pragma unroll
        for (int mf = 0; mf < 4; ++mf)
            af[mf] = *reinterpret_cast<const bf16x8*>(&As[cur][(wm * 4 + mf) * 512 + lane * 8]);
#pragma unroll
        for (int nf = 0; nf < 4; ++nf)
            bg[nf] = *reinterpret_cast<const bf16x8*>(&Bs[cur][(wn * 4 + nf) * 512 + lane * 8]);
#pragma unroll
        for (int mf = 0; mf < 4; ++mf)
#pragma unroll
            for (int nf = 0; nf < 4; ++nf)
                acc[mf][nf] = __builtin_amdgcn_mfma_f32_16x16x32_bf16(
                    af[mf], bg[nf], acc[mf][nf], 0, 0, 0);
        __syncthreads();
    }

    // ---- epilogue: score = sum_d tanh(kproj + q + bias + le) * sw ----
    const float K2 = 2.8853900817779268f;
    const float sb = score_b[0];
    float kqb[4], swv[4];
#pragma unroll
    for (int nf = 0; nf < 4; ++nf) {
        const int d = wn * 64 + nf * 16 + (lane & 15);
        kqb[nf] = qb_sm[d] * K2;
        swv[nf] = sw_sm[d];
    }
    const float* leB = le + ((size_t)(b * 4096 + kk0) + wm * 64 + ((lane >> 4) << 2)) * 128
                       + wn * 64 + (lane & 15);

#pragma unroll
    for (int mf = 0; mf < 4; ++mf) {
        float lv[16];
#pragma unroll
        for (int jj = 0; jj < 4; ++jj)
#pragma unroll
            for (int nf = 0; nf < 4; ++nf)
                lv[jj * 4 + nf] = leB[(size_t)(mf * 16 + jj) * 128 + nf * 16];
#pragma unroll
        for (int jj = 0; jj < 4; ++jj) {
            const int row_l = wm * 64 + mf * 16 + ((lane >> 4) << 2) + jj;
            float sum = 0.f;
#pragma unroll
            for (int nf = 0; nf < 4; ++nf) {
                const float m = fmaf(K2, lv[jj * 4 + nf], kqb[nf]);
                const float tt = fmaf(K2, acc[mf][nf][jj], m);
                const float y = __builtin_amdgcn_exp2f(tt);
                const float r = fmaf(-2.0f, __builtin_amdgcn_rcpf(y + 1.0f), 1.0f);
                sum = fmaf(r, swv[nf], sum);
            }
            sum += __shfl_xor(sum, 1);
            sum += __shfl_xor(sum, 2);
            sum += __shfl_xor(sum, 4);
            sum += __shfl_xor(sum, 8);
            if ((lane & 15) == 0) partial[row_l * 2 + wn] = sum;
        }
    }
    __syncthreads();
    if (t < 128) {
        align_out[(size_t)(b * 8 + h) * 4096 + kk0 + t] = partial[t * 2] + partial[t * 2 + 1] + sb;
    }
}

// ---------- K4: softmax over k ----------
__global__ __launch_bounds__(256) void softmax_kernel(float* __restrict__ align_o) {
    const int bh = blockIdx.x;
    float* row = align_o + (size_t)bh * 4096;
    const int t = threadIdx.x;
    float v[16];
    float m = -1e30f;
#pragma unroll
    for (int i = 0; i < 16; ++i) {
        v[i] = row[i * 256 + t];
        m = fmaxf(m, v[i]);
    }
#pragma unroll
    for (int off = 32; off; off >>= 1) m = fmaxf(m, __shfl_xor(m, off));
    __shared__ float sm[4], ss[4];
    const int wid = t >> 6;
    if ((t & 63) == 0) sm[wid] = m;
    __syncthreads();
    m = fmaxf(fmaxf(sm[0], sm[1]), fmaxf(sm[2], sm[3]));
    float s = 0.f;
#pragma unroll
    for (int i = 0; i < 16; ++i) {
        v[i] = __expf(v[i] - m);
        s += v[i];
    }
#pragma unroll
    for (int off = 32; off; off >>= 1) s += __shfl_xor(s, off);
    if ((t & 63) == 0) ss[wid] = s;
    __syncthreads();
    s = ss[0] + ss[1] + ss[2] + ss[3];
    const float inv = 1.f / s;
#pragma unroll
    for (int i = 0; i < 16; ++i) row[i * 256 + t] = v[i] * inv;
}

// ---------- K5: split-K context partials (float4) ----------
__global__ __launch_bounds__(256) void ctx_partial_kernel(
        const float* __restrict__ value, const float* __restrict__ align_o,
        float* __restrict__ pctx) {
    const int s = blockIdx.x;    // 0..31
    const int bh = blockIdx.y;   // 0..127
    const int b = bh >> 3, h = bh & 7;
    const int t = threadIdx.x;
    const int d4 = (t & 31) * 4;
    const int kg = t >> 5;
    const float* arow = align_o + (size_t)bh * 4096 + s * 128;
    const float* vbase = value + ((size_t)(b * 4096 + s * 128)) * 1024 + h * 128 + d4;
    float4 acc = {0.f, 0.f, 0.f, 0.f};
    for (int i = 0; i < 16; ++i) {
        const int kk = i * 8 + kg;
        const float a = arow[kk];
        const float4 v = *reinterpret_cast<const float4*>(vbase + (size_t)kk * 1024);
        acc.x += a * v.x; acc.y += a * v.y; acc.z += a * v.z; acc.w += a * v.w;
    }
    __shared__ float sm2[8][128];
    *reinterpret_cast<float4*>(&sm2[kg][d4]) = acc;
    __syncthreads();
    if (t < 128) {
        float s0 = 0.f;
#pragma unroll
        for (int gg = 0; gg < 8; ++gg) s0 += sm2[gg][t];
        pctx[((size_t)bh * 32 + s) * 128 + t] = s0;
    }
}

// ---------- K6: reduce context partials ----------
__global__ __launch_bounds__(128) void ctx_reduce_kernel(
        const float* __restrict__ pctx, float* __restrict__ out) {
    const int bh = blockIdx.x;
    const int t = threadIdx.x;
    float acc = 0.f;
    for (int s2 = 0; s2 < 32; ++s2) acc += pctx[((size_t)bh * 32 + s2) * 128 + t];
    out[(size_t)bh * 128 + t] = acc;
}

extern "C" void kernel_launch(void* const* d_in, const int* in_sizes, int n_in,
                              void* d_out, int out_size, void* d_ws, size_t ws_size,
                              hipStream_t stream) {
    const float* query   = (const float*)d_in[0];
    const float* key_in  = (const float*)d_in[1];
    const float* value   = (const float*)d_in[2];
    const float* pa      = (const float*)d_in[3];
    const float* conv_w  = (const float*)d_in[4];
    const float* conv_b  = (const float*)d_in[5];
    const float* w_u     = (const float*)d_in[6];
    const float* w_q     = (const float*)d_in[7];
    const float* w_v     = (const float*)d_in[8];
    const float* bias    = (const float*)d_in[9];
    const float* score_w = (const float*)d_in[10];
    const float* score_b = (const float*)d_in[11];

    float* out = (float*)d_out;
    float* ctx_out = out;                 // [128,128]
    float* align_out = out + 16384;       // [16,8,4096]

    char* ws = (char*)d_ws;
    const size_t OFF_Q    = 0;                        // 64 KB
    const size_t OFF_LOC  = 65536;                    // 2.62 MB
    const size_t OFF_WVT  = OFF_LOC + 2621440;        // 2 MB (tiled bf16)
    const size_t OFF_PCTX = OFF_WVT + 2097152;        // 2 MB
    const size_t OFF_LE   = OFF_PCTX + 2097152;       // 33.55 MB

    float* ws_q            = (float*)(ws + OFF_Q);
    float* ws_loc          = (float*)(ws + OFF_LOC);
    unsigned short* ws_wvT = (unsigned short*)(ws + OFF_WVT);
    float* ws_pctx         = (float*)(ws + OFF_PCTX);
    float* ws_le           = (float*)(ws + OFF_LE);

    hipLaunchKernelGGL(wv_tile_kernel, dim3(8, 32), dim3(256), 0, stream, w_v, ws_wvT);
    hipLaunchKernelGGL(qproj_kernel, dim3(128), dim3(128), 0, stream, query, w_q, ws_q);
    hipLaunchKernelGGL(loc_conv_kernel, dim3(16, 16), dim3(256), 0, stream, pa, conv_w, conv_b, ws_loc);
    hipLaunchKernelGGL(loc_energy_kernel, dim3(16, 32), dim3(256), 0, stream, ws_loc, w_u, ws_le);
    hipLaunchKernelGGL(gemm_score_kernel, dim3(4096), dim3(256), 0, stream,
                       key_in, ws_wvT, ws_le, ws_q, bias, score_w, score_b, align_out);
    hipLaunchKernelGGL(softmax_kernel, dim3(128), dim3(256), 0, stream, align_out);
    hipLaunchKernelGGL(ctx_partial_kernel, dim3(32, 128), dim3(256), 0, stream, value, align_out, ws_pctx);
    hipLaunchKernelGGL(ctx_reduce_kernel, dim3(128), dim3(128), 0, stream, ws_pctx, ctx_out);
}

// Round 8
// 326.636 us; speedup vs baseline: 1.4503x; 1.2419x over previous
//
#include <hip/hip_runtime.h>
#include <hip/hip_bf16.h>
#include <cstdint>

typedef __attribute__((ext_vector_type(8))) short bf16x8;
typedef __attribute__((ext_vector_type(4))) float f32x4;
typedef __attribute__((ext_vector_type(8))) unsigned short u16x8;
typedef __attribute__((ext_vector_type(4))) unsigned int u32x4;

__device__ __forceinline__ unsigned short f2bf(float f) {
    unsigned int u = __float_as_uint(f);
    unsigned int r = (u + 0x7fffu + ((u >> 16) & 1u)) >> 16;
    return (unsigned short)r;
}

__device__ __forceinline__ float tanh_fast(float x) {
    return 1.0f - 2.0f / (__expf(2.0f * x) + 1.0f);
}

#define GLDS(SRC, DST) __builtin_amdgcn_global_load_lds(                         \
        (const __attribute__((address_space(1))) void*)(SRC),                    \
        (__attribute__((address_space(3))) void*)(DST), 16, 0, 0)

// ---------- K0: w_v -> bf16 fragment-tiled B (per head) ----------
// out[h][kt][chunk c=cb*64+kg*16+cc][8]; col e=h*128+cb*16+cc, k(f)=kt*32+kg*8..+8
__global__ __launch_bounds__(256) void wv_tile_kernel(
        const float* __restrict__ wv, unsigned short* __restrict__ out) {
    __shared__ float tile[32][129];
    const int h = blockIdx.x;    // 0..7
    const int kt = blockIdx.y;   // 0..31
    const int t = threadIdx.x;
    for (int i = t; i < 1024; i += 256) {
        const int fl = i >> 5;
        const int e4 = (i & 31) * 4;
        const float4 v = *reinterpret_cast<const float4*>(
            wv + (size_t)(kt * 32 + fl) * 1024 + h * 128 + e4);
        tile[fl][e4 + 0] = v.x; tile[fl][e4 + 1] = v.y;
        tile[fl][e4 + 2] = v.z; tile[fl][e4 + 3] = v.w;
    }
    __syncthreads();
#pragma unroll
    for (int cc2 = 0; cc2 < 2; ++cc2) {
        const int c = cc2 * 256 + t;
        const int cb = c >> 6, kg = (c >> 4) & 3, ccl = c & 15;
        const int e_local = cb * 16 + ccl;
        u16x8 u;
#pragma unroll
        for (int jj = 0; jj < 8; ++jj) u[jj] = f2bf(tile[kg * 8 + jj][e_local]);
        *reinterpret_cast<u16x8*>(out + (((size_t)h * 32 + kt) * 512 + c) * 8) = u;
    }
}

// ---------- K1: q projection ----------
__global__ __launch_bounds__(128) void qproj_kernel(
        const float* __restrict__ query, const float* __restrict__ w_q,
        float* __restrict__ ws_q) {
    __shared__ float qs[1024];
    int bh = blockIdx.x;
    int b = bh >> 3, h = bh & 7;
    int t = threadIdx.x;
    for (int i = t; i < 1024; i += 128) qs[i] = query[(size_t)b * 1024 + i];
    __syncthreads();
    float acc = 0.f;
    const float* wcol = w_q + h * 128 + t;
    for (int f = 0; f < 1024; ++f) acc += qs[f] * wcol[(size_t)f * 1024];
    ws_q[(size_t)bh * 128 + t] = acc;
}

// ---------- K2: conv1d location features ----------
__global__ __launch_bounds__(256) void loc_conv_kernel(
        const float* __restrict__ pa, const float* __restrict__ conv_w,
        const float* __restrict__ conv_b, float* __restrict__ ws_loc) {
    __shared__ float pas[8][258];
    __shared__ float cw[240];
    __shared__ float cb[16];
    int b = blockIdx.x, k0 = blockIdx.y * 256;
    int t = threadIdx.x;
    for (int i = t; i < 8 * 258; i += 256) {
        int hh = i / 258, kk = i % 258;
        int gk = k0 + kk - 1;
        pas[hh][kk] = (gk >= 0 && gk < 4096) ? pa[((size_t)(b * 8 + hh)) * 4096 + gk] : 0.f;
    }
    if (t < 240) cw[t] = conv_w[t];
    if (t < 10) cb[t] = conv_b[t];
    __syncthreads();
#pragma unroll
    for (int c = 0; c < 10; ++c) {
        float acc = cb[c];
#pragma unroll
        for (int hh = 0; hh < 8; ++hh) {
            acc += pas[hh][t] * cw[(c * 8 + hh) * 3 + 0]
                 + pas[hh][t + 1] * cw[(c * 8 + hh) * 3 + 1]
                 + pas[hh][t + 2] * cw[(c * 8 + hh) * 3 + 2];
        }
        ws_loc[((size_t)(b * 10 + c)) * 4096 + k0 + t] = acc;
    }
}

// ---------- K2b: le[b,k,d] = tanh(sum_c loc[b,c,k]*w_u[c,d]) ----------
__global__ __launch_bounds__(256) void loc_energy_kernel(
        const float* __restrict__ ws_loc, const float* __restrict__ w_u,
        float* __restrict__ le) {
    __shared__ float loc_s[10][128];
    __shared__ float wu_s[10][128];
    const int b = blockIdx.x, k0 = blockIdx.y * 128;
    const int t = threadIdx.x;
    for (int i = t; i < 1280; i += 256) {
        const int c = i >> 7, r = i & 127;
        loc_s[c][r] = ws_loc[((size_t)(b * 10 + c)) * 4096 + k0 + r];
        wu_s[c][r] = w_u[i];
    }
    __syncthreads();
    const int k = t >> 1;
    const int d0 = (t & 1) * 64;
    float lc[10];
#pragma unroll
    for (int c = 0; c < 10; ++c) lc[c] = loc_s[c][k];
    float* dst = le + ((size_t)(b * 4096) + k0 + k) * 128 + d0;
#pragma unroll
    for (int dd = 0; dd < 64; dd += 4) {
        float4 o;
#pragma unroll
        for (int jj = 0; jj < 4; ++jj) {
            float s = 0.f;
#pragma unroll
            for (int c = 0; c < 10; ++c) s += lc[c] * wu_s[c][d0 + dd + jj];
            ((float*)&o)[jj] = tanh_fast(s);
        }
        *reinterpret_cast<float4*>(dst + dd) = o;
    }
}

// ---------- K3: fused bf16 MFMA GEMM + energy + score ----------
// BM=128 rows, BN=256 (2 heads), BK=32; 512 thr, 8 waves (2M x 4N), wave C=64x64.
// A: fp32 -> regs (2 iters ahead) -> v_cvt_pk_bf16 -> ds_write_b128 (contiguous/wave).
// B: pre-tiled bf16 via global_load_lds (2 per thread per kt = full 16KB coverage).
#define NT 32
__global__ __launch_bounds__(512) void gemm_score_kernel(
        const float* __restrict__ key_in, const unsigned short* __restrict__ wvT_tiled,
        const float* __restrict__ le,
        const float* __restrict__ ws_q, const float* __restrict__ bias,
        const float* __restrict__ score_w, const float* __restrict__ score_b,
        float* __restrict__ align_out) {
    __shared__ __align__(16) unsigned short As[2][4096];    // 16 KB
    __shared__ __align__(16) unsigned short Bs[2][8192];    // 32 KB
    __shared__ float qb_sm[256], sw_sm[128];
    __shared__ float partial[128][4];

    const int t = threadIdx.x;
    const int lane = t & 63, wid = t >> 6;
    const int wm = wid >> 2;          // 0..1 : M-half
    const int wn = wid & 3;           // 0..3 : (head, d-half)

    // XCD swizzle: the 4 head-pair blocks of one panel adjacent on one XCD
    const int fid = blockIdx.x;       // 0..2047
    const int x = fid & 7, j = fid >> 3;     // j: 0..255
    const int bm = x * 64 + (j >> 2);        // panel 0..511 (128 rows)
    const int hp = j & 3;                    // head-pair 0..3
    const int b = bm >> 5;
    const int kk0 = (bm & 31) << 7;

    if (t < 256) {
        const int hh = t >> 7, d = t & 127;
        qb_sm[t] = ws_q[(size_t)(b * 8 + hp * 2 + hh) * 128 + d] + bias[d];
        if (t < 128) sw_sm[t] = score_w[t];
    }

    // ---- A staging geometry: thread owns row r_=t>>2, k-seg ks=t&3 (8 floats) ----
    const int r_ = t >> 2, ks = t & 3;
    const float* aRow = key_in + ((size_t)(b * 4096 + kk0) + r_) * 1024 + ks * 8;
    const int dst0 = ((r_ >> 4) * 64 + ks * 16 + (r_ & 15)) * 8;   // ushort idx

    // ---- B staging: thread stages two 16B chunks of one head ----
    const unsigned short* bT = wvT_tiled
        + (size_t)(hp * 2 + (t >> 8)) * 131072 + (t & 255) * 8;
    const int dstB = (t >> 8) * 4096 + (t & 255) * 8;              // ushort idx

    float4 st0, st1;

#define LOADA(KT) {                                                               \
        const float* p_ = aRow + (KT) * 32;                                       \
        st0 = *reinterpret_cast<const float4*>(p_);                               \
        st1 = *reinterpret_cast<const float4*>(p_ + 4); }

#define WRITEA(BUF) {                                                             \
        __hip_bfloat162 h0_ = __float22bfloat162_rn({st0.x, st0.y});              \
        __hip_bfloat162 h1_ = __float22bfloat162_rn({st0.z, st0.w});              \
        __hip_bfloat162 h2_ = __float22bfloat162_rn({st1.x, st1.y});              \
        __hip_bfloat162 h3_ = __float22bfloat162_rn({st1.z, st1.w});              \
        u32x4 u_;                                                                 \
        u_[0] = *reinterpret_cast<unsigned int*>(&h0_);                           \
        u_[1] = *reinterpret_cast<unsigned int*>(&h1_);                           \
        u_[2] = *reinterpret_cast<unsigned int*>(&h2_);                           \
        u_[3] = *reinterpret_cast<unsigned int*>(&h3_);                           \
        *reinterpret_cast<u32x4*>(&As[BUF][dst0]) = u_; }

#define STAGE_B(BUF, KT) {                                                        \
        GLDS(bT + (size_t)(KT) * 4096, &Bs[BUF][dstB]);                           \
        GLDS(bT + (size_t)(KT) * 4096 + 2048, &Bs[BUF][dstB + 2048]); }

    f32x4 acc[4][4] = {};

    // prologue
    LOADA(0);
    STAGE_B(0, 0);
    WRITEA(0);
    LOADA(1);
    __syncthreads();

    for (int kt = 0; kt < NT; ++kt) {
        const int cur = kt & 1;
        if (kt < NT - 1) {
            STAGE_B(cur ^ 1, kt + 1);
            WRITEA(cur ^ 1);            // regs loaded last iteration
        }
        if (kt < NT - 2) LOADA(kt + 2); // issue early, lands under MFMA
        bf16x8 af[4], bg[4];
#pragma unroll
        for (int mf = 0; mf < 4; ++mf)
            af[mf] = *reinterpret_cast<const bf16x8*>(&As[cur][(wm * 4 + mf) * 512 + lane * 8]);
#pragma unroll
        for (int nf = 0; nf < 4; ++nf)
            bg[nf] = *reinterpret_cast<const bf16x8*>(
                &Bs[cur][(wn >> 1) * 4096 + ((wn & 1) * 4 + nf) * 512 + lane * 8]);
#pragma unroll
        for (int mf = 0; mf < 4; ++mf)
#pragma unroll
            for (int nf = 0; nf < 4; ++nf)
                acc[mf][nf] = __builtin_amdgcn_mfma_f32_16x16x32_bf16(
                    af[mf], bg[nf], acc[mf][nf], 0, 0, 0);
        __syncthreads();
    }

    // ---- epilogue: score = sum_d tanh(kproj + q + bias + le) * sw ----
    const float K2 = 2.8853900817779268f;
    const float sb = score_b[0];
    const int g = lane >> 4;
    float kqb[4], swv[4];
#pragma unroll
    for (int nf = 0; nf < 4; ++nf) {
        const int d128 = (wn & 1) * 64 + nf * 16 + (lane & 15);
        kqb[nf] = qb_sm[(wn >> 1) * 128 + d128] * K2;
        swv[nf] = sw_sm[d128];
    }
    const float* leB = le + ((size_t)(b * 4096 + kk0) + wm * 64 + g * 4) * 128
                       + (wn & 1) * 64 + (lane & 15);

#pragma unroll
    for (int mf = 0; mf < 4; ++mf) {
        float lv[16];
#pragma unroll
        for (int jj = 0; jj < 4; ++jj)
#pragma unroll
            for (int nf = 0; nf < 4; ++nf)
                lv[jj * 4 + nf] = leB[(size_t)(mf * 16 + jj) * 128 + nf * 16];
#pragma unroll
        for (int jj = 0; jj < 4; ++jj) {
            const int row_l = wm * 64 + mf * 16 + g * 4 + jj;
            float sum = 0.f;
#pragma unroll
            for (int nf = 0; nf < 4; ++nf) {
                const float m = fmaf(K2, lv[jj * 4 + nf], kqb[nf]);
                const float tt = fmaf(K2, acc[mf][nf][jj], m);
                const float y = __builtin_amdgcn_exp2f(tt);
                const float r = fmaf(-2.0f, __builtin_amdgcn_rcpf(y + 1.0f), 1.0f);
                sum = fmaf(r, swv[nf], sum);
            }
            sum += __shfl_xor(sum, 1);
            sum += __shfl_xor(sum, 2);
            sum += __shfl_xor(sum, 4);
            sum += __shfl_xor(sum, 8);
            if ((lane & 15) == 0) partial[row_l][wn] = sum;
        }
    }
    __syncthreads();
    if (t < 256) {
        const int r = t >> 1, hh = t & 1;
        const float sc = partial[r][hh * 2] + partial[r][hh * 2 + 1] + sb;
        align_out[(size_t)(b * 8 + hp * 2 + hh) * 4096 + kk0 + r] = sc;
    }
}

// ---------- K4: softmax over k ----------
__global__ __launch_bounds__(256) void softmax_kernel(float* __restrict__ align_o) {
    const int bh = blockIdx.x;
    float* row = align_o + (size_t)bh * 4096;
    const int t = threadIdx.x;
    float v[16];
    float m = -1e30f;
#pragma unroll
    for (int i = 0; i < 16; ++i) {
        v[i] = row[i * 256 + t];
        m = fmaxf(m, v[i]);
    }
#pragma unroll
    for (int off = 32; off; off >>= 1) m = fmaxf(m, __shfl_xor(m, off));
    __shared__ float sm[4], ss[4];
    const int wid = t >> 6;
    if ((t & 63) == 0) sm[wid] = m;
    __syncthreads();
    m = fmaxf(fmaxf(sm[0], sm[1]), fmaxf(sm[2], sm[3]));
    float s = 0.f;
#pragma unroll
    for (int i = 0; i < 16; ++i) {
        v[i] = __expf(v[i] - m);
        s += v[i];
    }
#pragma unroll
    for (int off = 32; off; off >>= 1) s += __shfl_xor(s, off);
    if ((t & 63) == 0) ss[wid] = s;
    __syncthreads();
    s = ss[0] + ss[1] + ss[2] + ss[3];
    const float inv = 1.f / s;
#pragma unroll
    for (int i = 0; i < 16; ++i) row[i * 256 + t] = v[i] * inv;
}

// ---------- K5: split-K context partials (float4) ----------
__global__ __launch_bounds__(256) void ctx_partial_kernel(
        const float* __restrict__ value, const float* __restrict__ align_o,
        float* __restrict__ pctx) {
    const int s = blockIdx.x;    // 0..31
    const int bh = blockIdx.y;   // 0..127
    const int b = bh >> 3, h = bh & 7;
    const int t = threadIdx.x;
    const int d4 = (t & 31) * 4;
    const int kg = t >> 5;
    const float* arow = align_o + (size_t)bh * 4096 + s * 128;
    const float* vbase = value + ((size_t)(b * 4096 + s * 128)) * 1024 + h * 128 + d4;
    float4 acc = {0.f, 0.f, 0.f, 0.f};
    for (int i = 0; i < 16; ++i) {
        const int kk = i * 8 + kg;
        const float a = arow[kk];
        const float4 v = *reinterpret_cast<const float4*>(vbase + (size_t)kk * 1024);
        acc.x += a * v.x; acc.y += a * v.y; acc.z += a * v.z; acc.w += a * v.w;
    }
    __shared__ float sm2[8][128];
    *reinterpret_cast<float4*>(&sm2[kg][d4]) = acc;
    __syncthreads();
    if (t < 128) {
        float s0 = 0.f;
#pragma unroll
        for (int gg = 0; gg < 8; ++gg) s0 += sm2[gg][t];
        pctx[((size_t)bh * 32 + s) * 128 + t] = s0;
    }
}

// ---------- K6: reduce context partials ----------
__global__ __launch_bounds__(128) void ctx_reduce_kernel(
        const float* __restrict__ pctx, float* __restrict__ out) {
    const int bh = blockIdx.x;
    const int t = threadIdx.x;
    float acc = 0.f;
    for (int s2 = 0; s2 < 32; ++s2) acc += pctx[((size_t)bh * 32 + s2) * 128 + t];
    out[(size_t)bh * 128 + t] = acc;
}

extern "C" void kernel_launch(void* const* d_in, const int* in_sizes, int n_in,
                              void* d_out, int out_size, void* d_ws, size_t ws_size,
                              hipStream_t stream) {
    const float* query   = (const float*)d_in[0];
    const float* key_in  = (const float*)d_in[1];
    const float* value   = (const float*)d_in[2];
    const float* pa      = (const float*)d_in[3];
    const float* conv_w  = (const float*)d_in[4];
    const float* conv_b  = (const float*)d_in[5];
    const float* w_u     = (const float*)d_in[6];
    const float* w_q     = (const float*)d_in[7];
    const float* w_v     = (const float*)d_in[8];
    const float* bias    = (const float*)d_in[9];
    const float* score_w = (const float*)d_in[10];
    const float* score_b = (const float*)d_in[11];

    float* out = (float*)d_out;
    float* ctx_out = out;                 // [128,128]
    float* align_out = out + 16384;       // [16,8,4096]

    char* ws = (char*)d_ws;
    const size_t OFF_Q    = 0;                        // 64 KB
    const size_t OFF_LOC  = 65536;                    // 2.62 MB
    const size_t OFF_WVT  = OFF_LOC + 2621440;        // 2 MB (tiled bf16)
    const size_t OFF_PCTX = OFF_WVT + 2097152;        // 2 MB
    const size_t OFF_LE   = OFF_PCTX + 2097152;       // 33.55 MB

    float* ws_q            = (float*)(ws + OFF_Q);
    float* ws_loc          = (float*)(ws + OFF_LOC);
    unsigned short* ws_wvT = (unsigned short*)(ws + OFF_WVT);
    float* ws_pctx         = (float*)(ws + OFF_PCTX);
    float* ws_le           = (float*)(ws + OFF_LE);

    hipLaunchKernelGGL(wv_tile_kernel, dim3(8, 32), dim3(256), 0, stream, w_v, ws_wvT);
    hipLaunchKernelGGL(qproj_kernel, dim3(128), dim3(128), 0, stream, query, w_q, ws_q);
    hipLaunchKernelGGL(loc_conv_kernel, dim3(16, 16), dim3(256), 0, stream, pa, conv_w, conv_b, ws_loc);
    hipLaunchKernelGGL(loc_energy_kernel, dim3(16, 32), dim3(256), 0, stream, ws_loc, w_u, ws_le);
    hipLaunchKernelGGL(gemm_score_kernel, dim3(2048), dim3(512), 0, stream,
                       key_in, ws_wvT, ws_le, ws_q, bias, score_w, score_b, align_out);
    hipLaunchKernelGGL(softmax_kernel, dim3(128), dim3(256), 0, stream, align_out);
    hipLaunchKernelGGL(ctx_partial_kernel, dim3(32, 128), dim3(256), 0, stream, value, align_out, ws_pctx);
    hipLaunchKernelGGL(ctx_reduce_kernel, dim3(128), dim3(128), 0, stream, ws_pctx, ctx_out);
}